// Round 5
// baseline (220.174 us; speedup 1.0000x reference)
//
#include <hip/hip_runtime.h>
#include <hip/hip_bf16.h>

#define NELL 9
#define CCH  128
#define DB   3
#define P3A  5
#define P2A  3
#define P1A  1
#define P3B  5
#define P2B  2
#define P1B  1

// typed load: F32 -> buffer is float32, else bf16 (upcast)
template <bool F32>
__device__ __forceinline__ float ld(const void* p, int idx) {
    if constexpr (F32) {
        return ((const float*)p)[idx];
    } else {
        unsigned int b = ((unsigned int)((const unsigned short*)p)[idx]) << 16;
        return __uint_as_float(b);
    }
}

template <bool F32>
__device__ __forceinline__ void body(
    const void* __restrict__ x, const void* __restrict__ y, int E,
    const void* __restrict__ U3a, const void* __restrict__ U2a, const void* __restrict__ U1a,
    const void* __restrict__ U3b, const void* __restrict__ U2b, const void* __restrict__ U1b,
    const void* __restrict__ W3a, const void* __restrict__ W2a, const void* __restrict__ W1a,
    const void* __restrict__ W3b, const void* __restrict__ W2b, const void* __restrict__ W1b,
    float* __restrict__ out, int b, int c)
{
    float xv[NELL];
#pragma unroll
    for (int i = 0; i < NELL; i++) xv[i] = ld<F32>(x, (b * CCH + c) * NELL + i);

    int e = 0;  // wave-uniform (b is uniform; y one-hot)
    for (int q = 0; q < E; q++)
        if (ld<F32>(y, b * E + q) > 0.5f) e = q;

    float t3a[P3A] = {}, t3b[DB * P3B] = {};
    float t2a[P2A] = {}, t2b[DB * P2B] = {};
    float t1a = 0.f, t1b[DB] = {};

    // full direct contraction: T_nu[d,p] = sum U_nu[d, ell..., p] * prod x
    for (int i = 0; i < NELL; i++) {
        const float xi = xv[i];
        for (int j = 0; j < NELL; j++) {
            const float xij = xi * xv[j];
            const int ij = i * 9 + j;
#pragma unroll
            for (int p = 0; p < P2A; p++)
                t2a[p] = fmaf(ld<F32>(U2a, ij * P2A + p), xij, t2a[p]);
#pragma unroll
            for (int d = 0; d < DB; d++)
#pragma unroll
                for (int p = 0; p < P2B; p++)
                    t2b[d * P2B + p] = fmaf(ld<F32>(U2b, (d * 81 + ij) * P2B + p), xij, t2b[d * P2B + p]);
            for (int k = 0; k < NELL; k++) {
                const float m = xij * xv[k];
                const int ijk = ij * 9 + k;
#pragma unroll
                for (int p = 0; p < P3A; p++)
                    t3a[p] = fmaf(ld<F32>(U3a, ijk * P3A + p), m, t3a[p]);
#pragma unroll
                for (int d = 0; d < DB; d++)
#pragma unroll
                    for (int p = 0; p < P3B; p++)
                        t3b[d * P3B + p] = fmaf(ld<F32>(U3b, (d * 729 + ijk) * P3B + p), m, t3b[d * P3B + p]);
            }
        }
    }
#pragma unroll
    for (int i = 0; i < NELL; i++) {
        t1a = fmaf(ld<F32>(U1a, i), xv[i], t1a);
#pragma unroll
        for (int d = 0; d < DB; d++)
            t1b[d] = fmaf(ld<F32>(U1b, d * 9 + i), xv[i], t1b[d]);
    }

    // per-element weights (coalesced across c)
    float o0 = 0.f;
#pragma unroll
    for (int p = 0; p < P3A; p++) o0 = fmaf(ld<F32>(W3a, (e * P3A + p) * CCH + c), t3a[p], o0);
#pragma unroll
    for (int p = 0; p < P2A; p++) o0 = fmaf(ld<F32>(W2a, (e * P2A + p) * CCH + c), t2a[p], o0);
    o0 = fmaf(ld<F32>(W1a, e * CCH + c), t1a, o0);

    float o1[DB] = {};
#pragma unroll
    for (int p = 0; p < P3B; p++) {
        const float w = ld<F32>(W3b, (e * P3B + p) * CCH + c);
#pragma unroll
        for (int d = 0; d < DB; d++) o1[d] = fmaf(w, t3b[d * P3B + p], o1[d]);
    }
#pragma unroll
    for (int p = 0; p < P2B; p++) {
        const float w = ld<F32>(W2b, (e * P2B + p) * CCH + c);
#pragma unroll
        for (int d = 0; d < DB; d++) o1[d] = fmaf(w, t2b[d * P2B + p], o1[d]);
    }
    {
        const float w = ld<F32>(W1b, e * CCH + c);
#pragma unroll
        for (int d = 0; d < DB; d++) o1[d] = fmaf(w, t1b[d], o1[d]);
    }

    // OUTPUT IS FLOAT32 (reference returns jnp.float32) — round-4 bug was bf16 stores.
    float* op = out + b * (CCH * 4);  // row = [128 (block0) | 384 (block1, c*3+d)]
    op[c] = o0;
#pragma unroll
    for (int d = 0; d < DB; d++) op[CCH + c * DB + d] = o1[d];
}

__global__ __launch_bounds__(CCH)
void sc_k(const void* __restrict__ x, const void* __restrict__ y, int E,
          const void* __restrict__ U3a, const void* __restrict__ U2a, const void* __restrict__ U1a,
          const void* __restrict__ U3b, const void* __restrict__ U2b, const void* __restrict__ U1b,
          const void* __restrict__ W3a, const void* __restrict__ W2a, const void* __restrict__ W1a,
          const void* __restrict__ W3b, const void* __restrict__ W2b, const void* __restrict__ W1b,
          float* __restrict__ out)
{
    const int c = threadIdx.x;
    const int b = blockIdx.x;

    // In-kernel dtype detection (wave-uniform): read x's first 64 half-words
    // as bf16. f32 data -> low half-words have random exponents (~24/32 insane);
    // bf16 data -> all sane.
    int insane = 0;
#pragma unroll
    for (int i = 0; i < 64; i++) {
        unsigned int bb = ((unsigned int)((const unsigned short*)x)[i]) << 16;
        float a = fabsf(__uint_as_float(bb));
        if (!(a == 0.0f || (a > 1e-10f && a < 1e10f))) insane++;  // NaN -> insane
    }
    if (insane > 8)
        body<true>(x, y, E, U3a, U2a, U1a, U3b, U2b, U1b,
                   W3a, W2a, W1a, W3b, W2b, W1b, out, b, c);
    else
        body<false>(x, y, E, U3a, U2a, U1a, U3b, U2b, U1b,
                    W3a, W2a, W1a, W3b, W2b, W1b, out, b, c);
}

extern "C" void kernel_launch(void* const* d_in, const int* in_sizes, int n_in,
                              void* d_out, int out_size, void* d_ws, size_t ws_size,
                              hipStream_t stream)
{
    (void)d_ws; (void)ws_size;

    // ---- order-agnostic classification by element counts ----
    int ix = 0;
    for (int i = 1; i < n_in; i++)
        if (in_sizes[i] > in_sizes[ix]) ix = i;
    int B = in_sizes[ix] / (CCH * NELL);
    bool ok = (n_in == 14) && (B > 0) && (in_sizes[ix] == B * CCH * NELL);

    int iy = -1, E = 0;
    if (ok) {
        for (int i = 0; i < n_in; i++) {
            if (i == ix) continue;
            if (in_sizes[i] % B == 0) {
                int Ec = in_sizes[i] / B;
                if (Ec >= 2 && Ec <= 1024) {
                    if (iy < 0) { iy = i; E = Ec; } else { ok = false; }
                }
            }
        }
        if (iy < 0) ok = false;
    }

    int iU1a = -1, iU2a = -1, iU3a = -1, iU1b = -1, iU2b = -1, iU3b = -1;
    int iW1a = -1, iW1b = -1, iW2a = -1, iW2b = -1, iW3a = -1, iW3b = -1;
    if (ok) {
        for (int i = 0; i < n_in && ok; i++) {
            if (i == ix || i == iy) continue;
            int s = in_sizes[i];
            if      (s == 9 * P1A)        { if (iU1a < 0) iU1a = i; else ok = false; }
            else if (s == 81 * P2A)       { if (iU2a < 0) iU2a = i; else ok = false; }
            else if (s == 729 * P3A)      { if (iU3a < 0) iU3a = i; else ok = false; }
            else if (s == 27 * P1B)       { if (iU1b < 0) iU1b = i; else ok = false; }
            else if (s == 243 * P2B)      { if (iU2b < 0) iU2b = i; else ok = false; }
            else if (s == 2187 * P3B)     { if (iU3b < 0) iU3b = i; else ok = false; }
            else if (s == E * P1A * CCH)  { if (iW1a < 0) iW1a = i; else if (iW1b < 0) iW1b = i; else ok = false; }
            else if (s == E * P2A * CCH)  { if (iW2a < 0) iW2a = i; else ok = false; }
            else if (s == E * P2B * CCH)  { if (iW2b < 0) iW2b = i; else ok = false; }
            else if (s == E * P3A * CCH)  { if (iW3a < 0) iW3a = i; else if (iW3b < 0) iW3b = i; else ok = false; }
            else ok = false;
        }
        if (iU1a < 0 || iU2a < 0 || iU3a < 0 || iU1b < 0 || iU2b < 0 || iU3b < 0 ||
            iW1a < 0 || iW1b < 0 || iW2a < 0 || iW2b < 0 || iW3a < 0 || iW3b < 0)
            ok = false;
    }

    if (!ok) {
        // dict-order fallback: x,y,U1_0,W1_0,U2_0,W2_0,U3_0,W3_0,U1_1,W1_1,U2_1,W2_1,U3_1,W3_1
        ix = 0; iy = 1;
        B = in_sizes[0] / (CCH * NELL);
        E = (B > 0) ? in_sizes[1] / B : 1;
        iU1a = 2;  iW1a = 3;  iU2a = 4;  iW2a = 5;  iU3a = 6;  iW3a = 7;
        iU1b = 8;  iW1b = 9;  iU2b = 10; iW2b = 11; iU3b = 12; iW3b = 13;
    }

    hipLaunchKernelGGL(sc_k, dim3(B), dim3(CCH), 0, stream,
                       d_in[ix], d_in[iy], E,
                       d_in[iU3a], d_in[iU2a], d_in[iU1a],
                       d_in[iU3b], d_in[iU2b], d_in[iU1b],
                       d_in[iW3a], d_in[iW2a], d_in[iW1a],
                       d_in[iW3b], d_in[iW2b], d_in[iW1b],
                       (float*)d_out);
}

// Round 6
// 189.863 us; speedup vs baseline: 1.1596x; 1.1596x over previous
//
#include <hip/hip_runtime.h>
#include <hip/hip_bf16.h>

#define NELL 9
#define CCH  128
#define DB   3
#define P3A  5
#define P2A  3
#define P1A  1
#define P3B  5
#define P2B  2
#define P1B  1
#define NT3  165
#define NT2  45
#define TTOT (NT3 + NT2 + NELL)   // 219 monomials (sorted triples, pairs, singles)

// ---------------------------------------------------------------------------
// Prep: build per-(e,c) fused coefficient table in ws:
//   ws[((e*CCH + c)*TTOT + t)*4 + d] = mult_t * sum_p U_nu[d, t, p] * W_nu[e, p, c]
// t-order: 165 triples (i<=j<=k), 45 pairs (i<=j), 9 singles — matches main loop.
// ---------------------------------------------------------------------------
__global__ void sc_prep(const float* __restrict__ U3a, const float* __restrict__ U2a,
                        const float* __restrict__ U1a, const float* __restrict__ U3b,
                        const float* __restrict__ U2b, const float* __restrict__ U1b,
                        const float* __restrict__ W3a, const float* __restrict__ W2a,
                        const float* __restrict__ W1a, const float* __restrict__ W3b,
                        const float* __restrict__ W2b, const float* __restrict__ W1b,
                        float* __restrict__ ws)
{
    const int ec = blockIdx.x;
    const int e = ec / CCH, c = ec % CCH;
    const int t = threadIdx.x;
    if (t >= TTOT) return;

    float v[4] = {0.f, 0.f, 0.f, 0.f};

    if (t < NT3) {
        // decode t -> (i<=j<=k)
        int idx = t, i = 0, j = 0, k = 0;
        bool done = false;
        for (i = 0; i < NELL && !done; i++)
            for (j = i; j < NELL && !done; j++)
                for (k = j; k < NELL; k++) {
                    if (idx == 0) { done = true; break; }
                    idx--;
                }
        i--; j--;  // undo post-increment of the aborted loops
        const float mult = (i == k) ? 1.f : ((i == j || j == k) ? 3.f : 6.f);
        const int ijk = (i * 9 + j) * 9 + k;
        for (int p = 0; p < P3A; p++)
            v[0] += U3a[ijk * P3A + p] * W3a[(e * P3A + p) * CCH + c];
        for (int d = 0; d < DB; d++)
            for (int p = 0; p < P3B; p++)
                v[1 + d] += U3b[(d * 729 + ijk) * P3B + p] * W3b[(e * P3B + p) * CCH + c];
        for (int d = 0; d < 4; d++) v[d] *= mult;
    } else if (t < NT3 + NT2) {
        int idx = t - NT3, i = 0, j = 0;
        bool done = false;
        for (i = 0; i < NELL && !done; i++)
            for (j = i; j < NELL; j++) {
                if (idx == 0) { done = true; break; }
                idx--;
            }
        i--;
        const float mult = (i == j) ? 1.f : 2.f;
        const int ij = i * 9 + j;
        for (int p = 0; p < P2A; p++)
            v[0] += U2a[ij * P2A + p] * W2a[(e * P2A + p) * CCH + c];
        for (int d = 0; d < DB; d++)
            for (int p = 0; p < P2B; p++)
                v[1 + d] += U2b[(d * 81 + ij) * P2B + p] * W2b[(e * P2B + p) * CCH + c];
        for (int d = 0; d < 4; d++) v[d] *= mult;
    } else {
        const int i = t - NT3 - NT2;
        v[0] = U1a[i] * W1a[e * CCH + c];
        for (int d = 0; d < DB; d++)
            v[1 + d] = U1b[d * 9 + i] * W1b[e * CCH + c];
    }

    float4* wp = (float4*)ws + (ec * TTOT + t);
    *wp = make_float4(v[0], v[1], v[2], v[3]);
}

// ---------------------------------------------------------------------------
// Main: one thread per (b,c). 219 independent dwordx4 loads (immediate offsets
// off one base) + 4 independent FMA chains. Monomial order matches prep.
// ---------------------------------------------------------------------------
__global__ __launch_bounds__(CCH)
void sc_main(const float* __restrict__ x, const float* __restrict__ y, int E,
             const float* __restrict__ ws, float* __restrict__ out)
{
    const int c = threadIdx.x;
    const int b = blockIdx.x;

    float xv[NELL];
    const float* xp = x + (b * CCH + c) * NELL;
#pragma unroll
    for (int i = 0; i < NELL; i++) xv[i] = xp[i];

    int e = 0;  // wave-uniform one-hot scan
    for (int q = 0; q < E; q++)
        if (y[b * E + q] > 0.5f) e = q;

    const float4* cp = (const float4*)ws + (e * CCH + c) * TTOT;

    float o0 = 0.f, o1 = 0.f, o2 = 0.f, o3 = 0.f;
    int t = 0;
#pragma unroll
    for (int i = 0; i < NELL; i++) {
#pragma unroll
        for (int j = i; j < NELL; j++) {
            const float pij = xv[i] * xv[j];
#pragma unroll
            for (int k = j; k < NELL; k++) {
                const float m = pij * xv[k];
                const float4 w = cp[t++];
                o0 = fmaf(w.x, m, o0);
                o1 = fmaf(w.y, m, o1);
                o2 = fmaf(w.z, m, o2);
                o3 = fmaf(w.w, m, o3);
            }
        }
    }
#pragma unroll
    for (int i = 0; i < NELL; i++) {
#pragma unroll
        for (int j = i; j < NELL; j++) {
            const float pij = xv[i] * xv[j];
            const float4 w = cp[t++];
            o0 = fmaf(w.x, pij, o0);
            o1 = fmaf(w.y, pij, o1);
            o2 = fmaf(w.z, pij, o2);
            o3 = fmaf(w.w, pij, o3);
        }
    }
#pragma unroll
    for (int i = 0; i < NELL; i++) {
        const float4 w = cp[t++];
        o0 = fmaf(w.x, xv[i], o0);
        o1 = fmaf(w.y, xv[i], o1);
        o2 = fmaf(w.z, xv[i], o2);
        o3 = fmaf(w.w, xv[i], o3);
    }

    float* op = out + b * (CCH * 4);  // [128 (block0) | 384 (block1, c*3+d)]
    op[c] = o0;
    op[CCH + c * DB + 0] = o1;
    op[CCH + c * DB + 1] = o2;
    op[CCH + c * DB + 2] = o3;
}

// ---------------------------------------------------------------------------
// Fallback: round-5 proven direct kernel (f32 in/out), used if ws too small
// or classification fails the strict check.
// ---------------------------------------------------------------------------
__global__ __launch_bounds__(CCH)
void sc_direct(const float* __restrict__ x, const float* __restrict__ y, int E,
               const float* __restrict__ U3a, const float* __restrict__ U2a, const float* __restrict__ U1a,
               const float* __restrict__ U3b, const float* __restrict__ U2b, const float* __restrict__ U1b,
               const float* __restrict__ W3a, const float* __restrict__ W2a, const float* __restrict__ W1a,
               const float* __restrict__ W3b, const float* __restrict__ W2b, const float* __restrict__ W1b,
               float* __restrict__ out)
{
    const int c = threadIdx.x;
    const int b = blockIdx.x;

    float xv[NELL];
#pragma unroll
    for (int i = 0; i < NELL; i++) xv[i] = x[(b * CCH + c) * NELL + i];

    int e = 0;
    for (int q = 0; q < E; q++)
        if (y[b * E + q] > 0.5f) e = q;

    float t3a[P3A] = {}, t3b[DB * P3B] = {};
    float t2a[P2A] = {}, t2b[DB * P2B] = {};
    float t1a = 0.f, t1b[DB] = {};

    for (int i = 0; i < NELL; i++) {
        const float xi = xv[i];
        for (int j = 0; j < NELL; j++) {
            const float xij = xi * xv[j];
            const int ij = i * 9 + j;
#pragma unroll
            for (int p = 0; p < P2A; p++)
                t2a[p] = fmaf(U2a[ij * P2A + p], xij, t2a[p]);
#pragma unroll
            for (int d = 0; d < DB; d++)
#pragma unroll
                for (int p = 0; p < P2B; p++)
                    t2b[d * P2B + p] = fmaf(U2b[(d * 81 + ij) * P2B + p], xij, t2b[d * P2B + p]);
            for (int k = 0; k < NELL; k++) {
                const float m = xij * xv[k];
                const int ijk = ij * 9 + k;
#pragma unroll
                for (int p = 0; p < P3A; p++)
                    t3a[p] = fmaf(U3a[ijk * P3A + p], m, t3a[p]);
#pragma unroll
                for (int d = 0; d < DB; d++)
#pragma unroll
                    for (int p = 0; p < P3B; p++)
                        t3b[d * P3B + p] = fmaf(U3b[(d * 729 + ijk) * P3B + p], m, t3b[d * P3B + p]);
            }
        }
    }
#pragma unroll
    for (int i = 0; i < NELL; i++) {
        t1a = fmaf(U1a[i], xv[i], t1a);
#pragma unroll
        for (int d = 0; d < DB; d++)
            t1b[d] = fmaf(U1b[d * 9 + i], xv[i], t1b[d]);
    }

    float o0 = 0.f;
#pragma unroll
    for (int p = 0; p < P3A; p++) o0 = fmaf(W3a[(e * P3A + p) * CCH + c], t3a[p], o0);
#pragma unroll
    for (int p = 0; p < P2A; p++) o0 = fmaf(W2a[(e * P2A + p) * CCH + c], t2a[p], o0);
    o0 = fmaf(W1a[e * CCH + c], t1a, o0);

    float o1[DB] = {};
#pragma unroll
    for (int p = 0; p < P3B; p++) {
        const float w = W3b[(e * P3B + p) * CCH + c];
#pragma unroll
        for (int d = 0; d < DB; d++) o1[d] = fmaf(w, t3b[d * P3B + p], o1[d]);
    }
#pragma unroll
    for (int p = 0; p < P2B; p++) {
        const float w = W2b[(e * P2B + p) * CCH + c];
#pragma unroll
        for (int d = 0; d < DB; d++) o1[d] = fmaf(w, t2b[d * P2B + p], o1[d]);
    }
    {
        const float w = W1b[e * CCH + c];
#pragma unroll
        for (int d = 0; d < DB; d++) o1[d] = fmaf(w, t1b[d], o1[d]);
    }

    float* op = out + b * (CCH * 4);
    op[c] = o0;
#pragma unroll
    for (int d = 0; d < DB; d++) op[CCH + c * DB + d] = o1[d];
}

extern "C" void kernel_launch(void* const* d_in, const int* in_sizes, int n_in,
                              void* d_out, int out_size, void* d_ws, size_t ws_size,
                              hipStream_t stream)
{
    // ---- order-agnostic classification by element counts (proven in r5) ----
    int ix = 0;
    for (int i = 1; i < n_in; i++)
        if (in_sizes[i] > in_sizes[ix]) ix = i;
    int B = in_sizes[ix] / (CCH * NELL);
    bool ok = (n_in == 14) && (B > 0) && (in_sizes[ix] == B * CCH * NELL);

    int iy = -1, E = 0;
    if (ok) {
        for (int i = 0; i < n_in; i++) {
            if (i == ix) continue;
            if (in_sizes[i] % B == 0) {
                int Ec = in_sizes[i] / B;
                if (Ec >= 2 && Ec <= 1024) {
                    if (iy < 0) { iy = i; E = Ec; } else { ok = false; }
                }
            }
        }
        if (iy < 0) ok = false;
    }

    int iU1a = -1, iU2a = -1, iU3a = -1, iU1b = -1, iU2b = -1, iU3b = -1;
    int iW1a = -1, iW1b = -1, iW2a = -1, iW2b = -1, iW3a = -1, iW3b = -1;
    if (ok) {
        for (int i = 0; i < n_in && ok; i++) {
            if (i == ix || i == iy) continue;
            int s = in_sizes[i];
            if      (s == 9 * P1A)        { if (iU1a < 0) iU1a = i; else ok = false; }
            else if (s == 81 * P2A)       { if (iU2a < 0) iU2a = i; else ok = false; }
            else if (s == 729 * P3A)      { if (iU3a < 0) iU3a = i; else ok = false; }
            else if (s == 27 * P1B)       { if (iU1b < 0) iU1b = i; else ok = false; }
            else if (s == 243 * P2B)      { if (iU2b < 0) iU2b = i; else ok = false; }
            else if (s == 2187 * P3B)     { if (iU3b < 0) iU3b = i; else ok = false; }
            else if (s == E * P1A * CCH)  { if (iW1a < 0) iW1a = i; else if (iW1b < 0) iW1b = i; else ok = false; }
            else if (s == E * P2A * CCH)  { if (iW2a < 0) iW2a = i; else ok = false; }
            else if (s == E * P2B * CCH)  { if (iW2b < 0) iW2b = i; else ok = false; }
            else if (s == E * P3A * CCH)  { if (iW3a < 0) iW3a = i; else if (iW3b < 0) iW3b = i; else ok = false; }
            else ok = false;
        }
        if (iU1a < 0 || iU2a < 0 || iU3a < 0 || iU1b < 0 || iU2b < 0 || iU3b < 0 ||
            iW1a < 0 || iW1b < 0 || iW2a < 0 || iW2b < 0 || iW3a < 0 || iW3b < 0)
            ok = false;
    }

    if (!ok) {
        // dict-order fallback
        ix = 0; iy = 1;
        B = in_sizes[0] / (CCH * NELL);
        E = (B > 0) ? in_sizes[1] / B : 1;
        iU1a = 2;  iW1a = 3;  iU2a = 4;  iW2a = 5;  iU3a = 6;  iW3a = 7;
        iU1b = 8;  iW1b = 9;  iU2b = 10; iW2b = 11; iU3b = 12; iW3b = 13;
    }

    const size_t ws_need = (size_t)E * CCH * TTOT * 4 * sizeof(float);

    if (ws_size >= ws_need) {
        hipLaunchKernelGGL(sc_prep, dim3(E * CCH), dim3(256), 0, stream,
                           (const float*)d_in[iU3a], (const float*)d_in[iU2a], (const float*)d_in[iU1a],
                           (const float*)d_in[iU3b], (const float*)d_in[iU2b], (const float*)d_in[iU1b],
                           (const float*)d_in[iW3a], (const float*)d_in[iW2a], (const float*)d_in[iW1a],
                           (const float*)d_in[iW3b], (const float*)d_in[iW2b], (const float*)d_in[iW1b],
                           (float*)d_ws);
        hipLaunchKernelGGL(sc_main, dim3(B), dim3(CCH), 0, stream,
                           (const float*)d_in[ix], (const float*)d_in[iy], E,
                           (const float*)d_ws, (float*)d_out);
    } else {
        hipLaunchKernelGGL(sc_direct, dim3(B), dim3(CCH), 0, stream,
                           (const float*)d_in[ix], (const float*)d_in[iy], E,
                           (const float*)d_in[iU3a], (const float*)d_in[iU2a], (const float*)d_in[iU1a],
                           (const float*)d_in[iU3b], (const float*)d_in[iU2b], (const float*)d_in[iU1b],
                           (const float*)d_in[iW3a], (const float*)d_in[iW2a], (const float*)d_in[iW1a],
                           (const float*)d_in[iW3b], (const float*)d_in[iW2b], (const float*)d_in[iW1b],
                           (float*)d_out);
    }
}

// Round 7
// 64.663 us; speedup vs baseline: 3.4050x; 2.9362x over previous
//
#include <hip/hip_runtime.h>
#include <hip/hip_bf16.h>

#define NELL 9
#define CCH  128
#define DB   3
#define P3A  5
#define P2A  3
#define P1A  1
#define P3B  5
#define P2B  2
#define P1B  1
#define NT3  165
#define NT2  45
#define TTOT (NT3 + NT2 + NELL)   // 219 monomials (sorted triples, pairs, singles)

// ---------------------------------------------------------------------------
// Prep: fused coefficient table, COALESCED layout [e][t][c] (float4 over d):
//   ws4[(e*TTOT + t)*CCH + c] = mult_t * { sum_p U_nu[d,t,p] * W_nu[e,p,c] }_{d=0..3}
// One block per (e,t); lane = c. W reads and ws writes are coalesced.
// ---------------------------------------------------------------------------
__global__ __launch_bounds__(CCH)
void sc_prep(const float* __restrict__ U3a, const float* __restrict__ U2a,
             const float* __restrict__ U1a, const float* __restrict__ U3b,
             const float* __restrict__ U2b, const float* __restrict__ U1b,
             const float* __restrict__ W3a, const float* __restrict__ W2a,
             const float* __restrict__ W1a, const float* __restrict__ W3b,
             const float* __restrict__ W2b, const float* __restrict__ W1b,
             float* __restrict__ ws)
{
    const int bt = blockIdx.x;
    const int e = bt / TTOT, t = bt % TTOT;
    const int c = threadIdx.x;

    float v[4] = {0.f, 0.f, 0.f, 0.f};

    if (t < NT3) {
        // decode t -> (i<=j<=k), uniform per block
        int idx = t, i = 0, j = 0, k = 0;
        bool done = false;
        for (i = 0; i < NELL && !done; i++)
            for (j = i; j < NELL && !done; j++)
                for (k = j; k < NELL; k++) {
                    if (idx == 0) { done = true; break; }
                    idx--;
                }
        i--; j--;  // undo post-increment of aborted loops
        const float mult = (i == k) ? 1.f : ((i == j || j == k) ? 3.f : 6.f);
        const int ijk = (i * 9 + j) * 9 + k;
        for (int p = 0; p < P3A; p++)
            v[0] += U3a[ijk * P3A + p] * W3a[(e * P3A + p) * CCH + c];
        for (int d = 0; d < DB; d++)
            for (int p = 0; p < P3B; p++)
                v[1 + d] += U3b[(d * 729 + ijk) * P3B + p] * W3b[(e * P3B + p) * CCH + c];
        for (int d = 0; d < 4; d++) v[d] *= mult;
    } else if (t < NT3 + NT2) {
        int idx = t - NT3, i = 0, j = 0;
        bool done = false;
        for (i = 0; i < NELL && !done; i++)
            for (j = i; j < NELL; j++) {
                if (idx == 0) { done = true; break; }
                idx--;
            }
        i--;
        const float mult = (i == j) ? 1.f : 2.f;
        const int ij = i * 9 + j;
        for (int p = 0; p < P2A; p++)
            v[0] += U2a[ij * P2A + p] * W2a[(e * P2A + p) * CCH + c];
        for (int d = 0; d < DB; d++)
            for (int p = 0; p < P2B; p++)
                v[1 + d] += U2b[(d * 81 + ij) * P2B + p] * W2b[(e * P2B + p) * CCH + c];
        for (int d = 0; d < 4; d++) v[d] *= mult;
    } else {
        const int i = t - NT3 - NT2;
        v[0] = U1a[i] * W1a[e * CCH + c];
        for (int d = 0; d < DB; d++)
            v[1 + d] = U1b[d * 9 + i] * W1b[e * CCH + c];
    }

    ((float4*)ws)[(size_t)bt * CCH + c] = make_float4(v[0], v[1], v[2], v[3]);
}

// ---------------------------------------------------------------------------
// Main: one thread per (b,c). 219 COALESCED dwordx4 loads (lane-consecutive)
// + 4 independent FMA chains. Monomial order matches prep.
// ---------------------------------------------------------------------------
__global__ __launch_bounds__(CCH)
void sc_main(const float* __restrict__ x, const float* __restrict__ y, int E,
             const float* __restrict__ ws, float* __restrict__ out)
{
    const int c = threadIdx.x;
    const int b = blockIdx.x;

    float xv[NELL];
    const float* xp = x + (b * CCH + c) * NELL;
#pragma unroll
    for (int i = 0; i < NELL; i++) xv[i] = xp[i];

    int e = 0;  // wave-uniform one-hot scan
    for (int q = 0; q < E; q++)
        if (y[b * E + q] > 0.5f) e = q;

    // coalesced: at monomial t, lane c reads cp[t*CCH] (consecutive across lanes)
    const float4* cp = (const float4*)ws + (size_t)e * TTOT * CCH + c;

    float o0 = 0.f, o1 = 0.f, o2 = 0.f, o3 = 0.f;
    int t = 0;
#pragma unroll
    for (int i = 0; i < NELL; i++) {
#pragma unroll
        for (int j = i; j < NELL; j++) {
            const float pij = xv[i] * xv[j];
#pragma unroll
            for (int k = j; k < NELL; k++) {
                const float m = pij * xv[k];
                const float4 w = cp[(t++) * CCH];
                o0 = fmaf(w.x, m, o0);
                o1 = fmaf(w.y, m, o1);
                o2 = fmaf(w.z, m, o2);
                o3 = fmaf(w.w, m, o3);
            }
        }
    }
#pragma unroll
    for (int i = 0; i < NELL; i++) {
#pragma unroll
        for (int j = i; j < NELL; j++) {
            const float pij = xv[i] * xv[j];
            const float4 w = cp[(t++) * CCH];
            o0 = fmaf(w.x, pij, o0);
            o1 = fmaf(w.y, pij, o1);
            o2 = fmaf(w.z, pij, o2);
            o3 = fmaf(w.w, pij, o3);
        }
    }
#pragma unroll
    for (int i = 0; i < NELL; i++) {
        const float4 w = cp[(t++) * CCH];
        o0 = fmaf(w.x, xv[i], o0);
        o1 = fmaf(w.y, xv[i], o1);
        o2 = fmaf(w.z, xv[i], o2);
        o3 = fmaf(w.w, xv[i], o3);
    }

    float* op = out + b * (CCH * 4);  // [128 (block0) | 384 (block1, c*3+d)]
    op[c] = o0;
    op[CCH + c * DB + 0] = o1;
    op[CCH + c * DB + 1] = o2;
    op[CCH + c * DB + 2] = o3;
}

// ---------------------------------------------------------------------------
// Fallback: round-5 proven direct kernel (f32 in/out), used if ws too small
// or classification fails the strict check.
// ---------------------------------------------------------------------------
__global__ __launch_bounds__(CCH)
void sc_direct(const float* __restrict__ x, const float* __restrict__ y, int E,
               const float* __restrict__ U3a, const float* __restrict__ U2a, const float* __restrict__ U1a,
               const float* __restrict__ U3b, const float* __restrict__ U2b, const float* __restrict__ U1b,
               const float* __restrict__ W3a, const float* __restrict__ W2a, const float* __restrict__ W1a,
               const float* __restrict__ W3b, const float* __restrict__ W2b, const float* __restrict__ W1b,
               float* __restrict__ out)
{
    const int c = threadIdx.x;
    const int b = blockIdx.x;

    float xv[NELL];
#pragma unroll
    for (int i = 0; i < NELL; i++) xv[i] = x[(b * CCH + c) * NELL + i];

    int e = 0;
    for (int q = 0; q < E; q++)
        if (y[b * E + q] > 0.5f) e = q;

    float t3a[P3A] = {}, t3b[DB * P3B] = {};
    float t2a[P2A] = {}, t2b[DB * P2B] = {};
    float t1a = 0.f, t1b[DB] = {};

    for (int i = 0; i < NELL; i++) {
        const float xi = xv[i];
        for (int j = 0; j < NELL; j++) {
            const float xij = xi * xv[j];
            const int ij = i * 9 + j;
#pragma unroll
            for (int p = 0; p < P2A; p++)
                t2a[p] = fmaf(U2a[ij * P2A + p], xij, t2a[p]);
#pragma unroll
            for (int d = 0; d < DB; d++)
#pragma unroll
                for (int p = 0; p < P2B; p++)
                    t2b[d * P2B + p] = fmaf(U2b[(d * 81 + ij) * P2B + p], xij, t2b[d * P2B + p]);
            for (int k = 0; k < NELL; k++) {
                const float m = xij * xv[k];
                const int ijk = ij * 9 + k;
#pragma unroll
                for (int p = 0; p < P3A; p++)
                    t3a[p] = fmaf(U3a[ijk * P3A + p], m, t3a[p]);
#pragma unroll
                for (int d = 0; d < DB; d++)
#pragma unroll
                    for (int p = 0; p < P3B; p++)
                        t3b[d * P3B + p] = fmaf(U3b[(d * 729 + ijk) * P3B + p], m, t3b[d * P3B + p]);
            }
        }
    }
#pragma unroll
    for (int i = 0; i < NELL; i++) {
        t1a = fmaf(U1a[i], xv[i], t1a);
#pragma unroll
        for (int d = 0; d < DB; d++)
            t1b[d] = fmaf(U1b[d * 9 + i], xv[i], t1b[d]);
    }

    float o0 = 0.f;
#pragma unroll
    for (int p = 0; p < P3A; p++) o0 = fmaf(W3a[(e * P3A + p) * CCH + c], t3a[p], o0);
#pragma unroll
    for (int p = 0; p < P2A; p++) o0 = fmaf(W2a[(e * P2A + p) * CCH + c], t2a[p], o0);
    o0 = fmaf(W1a[e * CCH + c], t1a, o0);

    float o1[DB] = {};
#pragma unroll
    for (int p = 0; p < P3B; p++) {
        const float w = W3b[(e * P3B + p) * CCH + c];
#pragma unroll
        for (int d = 0; d < DB; d++) o1[d] = fmaf(w, t3b[d * P3B + p], o1[d]);
    }
#pragma unroll
    for (int p = 0; p < P2B; p++) {
        const float w = W2b[(e * P2B + p) * CCH + c];
#pragma unroll
        for (int d = 0; d < DB; d++) o1[d] = fmaf(w, t2b[d * P2B + p], o1[d]);
    }
    {
        const float w = W1b[e * CCH + c];
#pragma unroll
        for (int d = 0; d < DB; d++) o1[d] = fmaf(w, t1b[d], o1[d]);
    }

    float* op = out + b * (CCH * 4);
    op[c] = o0;
#pragma unroll
    for (int d = 0; d < DB; d++) op[CCH + c * DB + d] = o1[d];
}

extern "C" void kernel_launch(void* const* d_in, const int* in_sizes, int n_in,
                              void* d_out, int out_size, void* d_ws, size_t ws_size,
                              hipStream_t stream)
{
    // ---- order-agnostic classification by element counts (proven in r5) ----
    int ix = 0;
    for (int i = 1; i < n_in; i++)
        if (in_sizes[i] > in_sizes[ix]) ix = i;
    int B = in_sizes[ix] / (CCH * NELL);
    bool ok = (n_in == 14) && (B > 0) && (in_sizes[ix] == B * CCH * NELL);

    int iy = -1, E = 0;
    if (ok) {
        for (int i = 0; i < n_in; i++) {
            if (i == ix) continue;
            if (in_sizes[i] % B == 0) {
                int Ec = in_sizes[i] / B;
                if (Ec >= 2 && Ec <= 1024) {
                    if (iy < 0) { iy = i; E = Ec; } else { ok = false; }
                }
            }
        }
        if (iy < 0) ok = false;
    }

    int iU1a = -1, iU2a = -1, iU3a = -1, iU1b = -1, iU2b = -1, iU3b = -1;
    int iW1a = -1, iW1b = -1, iW2a = -1, iW2b = -1, iW3a = -1, iW3b = -1;
    if (ok) {
        for (int i = 0; i < n_in && ok; i++) {
            if (i == ix || i == iy) continue;
            int s = in_sizes[i];
            if      (s == 9 * P1A)        { if (iU1a < 0) iU1a = i; else ok = false; }
            else if (s == 81 * P2A)       { if (iU2a < 0) iU2a = i; else ok = false; }
            else if (s == 729 * P3A)      { if (iU3a < 0) iU3a = i; else ok = false; }
            else if (s == 27 * P1B)       { if (iU1b < 0) iU1b = i; else ok = false; }
            else if (s == 243 * P2B)      { if (iU2b < 0) iU2b = i; else ok = false; }
            else if (s == 2187 * P3B)     { if (iU3b < 0) iU3b = i; else ok = false; }
            else if (s == E * P1A * CCH)  { if (iW1a < 0) iW1a = i; else if (iW1b < 0) iW1b = i; else ok = false; }
            else if (s == E * P2A * CCH)  { if (iW2a < 0) iW2a = i; else ok = false; }
            else if (s == E * P2B * CCH)  { if (iW2b < 0) iW2b = i; else ok = false; }
            else if (s == E * P3A * CCH)  { if (iW3a < 0) iW3a = i; else if (iW3b < 0) iW3b = i; else ok = false; }
            else ok = false;
        }
        if (iU1a < 0 || iU2a < 0 || iU3a < 0 || iU1b < 0 || iU2b < 0 || iU3b < 0 ||
            iW1a < 0 || iW1b < 0 || iW2a < 0 || iW2b < 0 || iW3a < 0 || iW3b < 0)
            ok = false;
    }

    if (!ok) {
        // dict-order fallback
        ix = 0; iy = 1;
        B = in_sizes[0] / (CCH * NELL);
        E = (B > 0) ? in_sizes[1] / B : 1;
        iU1a = 2;  iW1a = 3;  iU2a = 4;  iW2a = 5;  iU3a = 6;  iW3a = 7;
        iU1b = 8;  iW1b = 9;  iU2b = 10; iW2b = 11; iU3b = 12; iW3b = 13;
    }

    const size_t ws_need = (size_t)E * CCH * TTOT * 4 * sizeof(float);

    if (ws_size >= ws_need) {
        hipLaunchKernelGGL(sc_prep, dim3(E * TTOT), dim3(CCH), 0, stream,
                           (const float*)d_in[iU3a], (const float*)d_in[iU2a], (const float*)d_in[iU1a],
                           (const float*)d_in[iU3b], (const float*)d_in[iU2b], (const float*)d_in[iU1b],
                           (const float*)d_in[iW3a], (const float*)d_in[iW2a], (const float*)d_in[iW1a],
                           (const float*)d_in[iW3b], (const float*)d_in[iW2b], (const float*)d_in[iW1b],
                           (float*)d_ws);
        hipLaunchKernelGGL(sc_main, dim3(B), dim3(CCH), 0, stream,
                           (const float*)d_in[ix], (const float*)d_in[iy], E,
                           (const float*)d_ws, (float*)d_out);
    } else {
        hipLaunchKernelGGL(sc_direct, dim3(B), dim3(CCH), 0, stream,
                           (const float*)d_in[ix], (const float*)d_in[iy], E,
                           (const float*)d_in[iU3a], (const float*)d_in[iU2a], (const float*)d_in[iU1a],
                           (const float*)d_in[iU3b], (const float*)d_in[iU2b], (const float*)d_in[iU1b],
                           (const float*)d_in[iW3a], (const float*)d_in[iW2a], (const float*)d_in[iW1a],
                           (const float*)d_in[iW3b], (const float*)d_in[iW2b], (const float*)d_in[iW1b],
                           (float*)d_out);
    }
}